// Round 3
// baseline (381.844 us; speedup 1.0000x reference)
//
#include <hip/hip_runtime.h>
#include <hip/hip_bf16.h>

// EdgeProposer: probs/directions/relations heads over gathered belief pairs.
// INPUTS ARE FLOAT32 (reference dtype; R1/R2 NaN proved f32-read-as-bf16),
// OUTPUT IS FLOAT32. MFMA path converts to bf16: prep transposes+converts
// weights into ws; main stages belief slices f32->bf16 in LDS.
// Layer-1 of all three heads = feats[N x 1536] @ Wcat[1536 x 320] (96% of
// FLOPs) via mfma_f32_16x16x32_bf16; layer-2 + scalar heads per 64-row block.

#define DD 512
#define K3 1536
#define LDA 72      // 64 + 8 pad
#define LDACT 328   // 320 + 8 pad
#define LDH 72

typedef short bf16x8 __attribute__((ext_vector_type(8)));
typedef float f32x4 __attribute__((ext_vector_type(4)));

__device__ inline float b2f(short s) {
    union { float f; unsigned u; } v;
    v.u = ((unsigned)(unsigned short)s) << 16;
    return v.f;
}
__device__ inline short f2b(float f) {
    union { float fl; unsigned u; } v;
    v.fl = f;
    unsigned x = v.u;
    unsigned r = x + 0x7fffu + ((x >> 16) & 1u);
    return (short)(r >> 16);
}

// ---- prep: transpose/concat f32 weights -> bf16 in workspace ----
#define WT_ELEMS (320 * 1536)
#define P2T_OFF WT_ELEMS
#define R2T_OFF (WT_ELEMS + 64 * 128)
#define PREP_TOT (WT_ELEMS + 2 * 64 * 128)

__global__ void prep_kernel(const float* __restrict__ pw1,
                            const float* __restrict__ dw1,
                            const float* __restrict__ rw1,
                            const float* __restrict__ pw2,
                            const float* __restrict__ rw2,
                            short* __restrict__ ws) {
    int i = blockIdx.x * 256 + threadIdx.x;
    if (i < WT_ELEMS) {
        int n = i / K3, k = i - n * K3;
        float v;
        if (n < 128)      v = pw1[k * 128 + n];
        else if (n < 192) v = dw1[k * 64 + (n - 128)];
        else              v = rw1[k * 128 + (n - 192)];
        ws[i] = f2b(v);
    } else if (i < R2T_OFF) {
        int j = i - P2T_OFF;
        int n = j >> 7, k = j & 127;
        ws[i] = f2b(pw2[k * 64 + n]);
    } else if (i < PREP_TOT) {
        int j = i - R2T_OFF;
        int n = j >> 7, k = j & 127;
        ws[i] = f2b(rw2[k * 64 + n]);
    }
}

// ---- main fused kernel: 64 pairs per block, 256 threads (4 waves) ----
__global__ __launch_bounds__(256, 2) void edge_main(
    const float* __restrict__ beliefs,
    const int* __restrict__ src_idx, const int* __restrict__ tgt_idx,
    const float* __restrict__ pb1, const float* __restrict__ db1,
    const float* __restrict__ rb1,
    const float* __restrict__ pb2, const float* __restrict__ pw3,
    const float* __restrict__ pb3,
    const float* __restrict__ dw2, const float* __restrict__ db2,
    const float* __restrict__ rb2,
    const short* __restrict__ WT, const short* __restrict__ pw2T,
    const short* __restrict__ rw2T,
    float* __restrict__ out, int N)
{
    __shared__ __align__(16) char smem_u[64 * LDACT * 2];   // 41984 B
    __shared__ __align__(16) short h2s[64][LDH];            // 9216 B
    __shared__ int sIdx[64], tIdx[64];

    short (*As)[64][LDA] = (short (*)[64][LDA])smem_u;      // 27648 B used
    short (*acts)[LDACT] = (short (*)[LDACT])smem_u;

    const int t = threadIdx.x;
    const int r0 = blockIdx.x * 64;
    const int w = t >> 6, lane = t & 63, q = lane >> 4, ln = lane & 15;

    if (t < 64) sIdx[t] = src_idx[r0 + t] * DD;
    else if (t < 128) tIdx[t - 64] = tgt_idx[r0 + t - 64] * DD;
    __syncthreads();

    f32x4 acc[5][4];
#pragma unroll
    for (int ct = 0; ct < 5; ct++)
#pragma unroll
        for (int rt = 0; rt < 4; rt++) acc[ct][rt] = (f32x4)(0.f);

    const int rrow = t >> 2, cb = (t & 3) * 16;
    const int srow = sIdx[rrow], trow = tIdx[rrow];

    for (int k0 = 0; k0 < DD; k0 += 64) {
        // stage src / tgt / |src-tgt| slices [64 x 64], f32 -> bf16
        const float4* ps = (const float4*)(beliefs + srow + k0 + cb);
        const float4* pt = (const float4*)(beliefs + trow + k0 + cb);
        short sb[16] __attribute__((aligned(16)));
        short tb[16] __attribute__((aligned(16)));
        short ab[16] __attribute__((aligned(16)));
#pragma unroll
        for (int j = 0; j < 4; j++) {
            float4 s4 = ps[j];
            float4 t4 = pt[j];
            float ss[4] = {s4.x, s4.y, s4.z, s4.w};
            float tt[4] = {t4.x, t4.y, t4.z, t4.w};
#pragma unroll
            for (int e = 0; e < 4; e++) {
                int idx = j * 4 + e;
                sb[idx] = f2b(ss[e]);
                tb[idx] = f2b(tt[e]);
                ab[idx] = f2b(fabsf(ss[e] - tt[e]));
            }
        }
        *(bf16x8*)&As[0][rrow][cb]     = *(const bf16x8*)&sb[0];
        *(bf16x8*)&As[0][rrow][cb + 8] = *(const bf16x8*)&sb[8];
        *(bf16x8*)&As[1][rrow][cb]     = *(const bf16x8*)&tb[0];
        *(bf16x8*)&As[1][rrow][cb + 8] = *(const bf16x8*)&tb[8];
        *(bf16x8*)&As[2][rrow][cb]     = *(const bf16x8*)&ab[0];
        *(bf16x8*)&As[2][rrow][cb + 8] = *(const bf16x8*)&ab[8];
        __syncthreads();

#pragma unroll
        for (int kk = 0; kk < 64; kk += 32) {
#pragma unroll
            for (int seg = 0; seg < 3; seg++) {
                bf16x8 af[4];
#pragma unroll
                for (int rt = 0; rt < 4; rt++)
                    af[rt] = *(const bf16x8*)&As[seg][rt * 16 + ln][kk + q * 8];
#pragma unroll
                for (int ct = 0; ct < 5; ct++) {
                    int col = w * 80 + ct * 16 + ln;
                    bf16x8 bfr = *(const bf16x8*)(WT + (size_t)col * K3 +
                                                  seg * DD + k0 + kk + q * 8);
#pragma unroll
                    for (int rt = 0; rt < 4; rt++)
                        acc[ct][rt] = __builtin_amdgcn_mfma_f32_16x16x32_bf16(
                            af[rt], bfr, acc[ct][rt], 0, 0, 0);
                }
            }
        }
        __syncthreads();
    }

    // phase B: bias + relu -> acts[64][320] (bf16). C/D: col=lane&15, row=q*4+reg.
#pragma unroll
    for (int ct = 0; ct < 5; ct++) {
        int col = w * 80 + ct * 16 + ln;
        float bias = (col < 128) ? pb1[col]
                   : (col < 192) ? db1[col - 128]
                                 : rb1[col - 192];
#pragma unroll
        for (int rt = 0; rt < 4; rt++)
#pragma unroll
            for (int i = 0; i < 4; i++) {
                int row = rt * 16 + q * 4 + i;
                float v = acc[ct][rt][i] + bias;
                acts[row][col] = f2b(fmaxf(v, 0.f));
            }
    }
    __syncthreads();

    // phase C1: relations = relu1_r[64x128] @ rw2 + rb2
    {
        f32x4 rc[4];
#pragma unroll
        for (int rt = 0; rt < 4; rt++) rc[rt] = (f32x4)(0.f);
#pragma unroll
        for (int ks = 0; ks < 4; ks++) {
            bf16x8 bfr = *(const bf16x8*)(rw2T + (w * 16 + ln) * 128 +
                                          ks * 32 + q * 8);
#pragma unroll
            for (int rt = 0; rt < 4; rt++) {
                bf16x8 afr = *(const bf16x8*)&acts[rt * 16 + ln][192 + ks * 32 + q * 8];
                rc[rt] = __builtin_amdgcn_mfma_f32_16x16x32_bf16(afr, bfr, rc[rt], 0, 0, 0);
            }
        }
        int col = w * 16 + ln;
        float bias = rb2[col];
        float* rel = out + 2 * (size_t)N;
#pragma unroll
        for (int rt = 0; rt < 4; rt++)
#pragma unroll
            for (int i = 0; i < 4; i++) {
                int row = rt * 16 + q * 4 + i;
                rel[(size_t)(r0 + row) * 64 + col] = rc[rt][i] + bias;
            }
    }

    // phase C2: h2 = relu(relu1_p[64x128] @ pw2 + pb2) -> h2s
    {
        f32x4 pc[4];
#pragma unroll
        for (int rt = 0; rt < 4; rt++) pc[rt] = (f32x4)(0.f);
#pragma unroll
        for (int ks = 0; ks < 4; ks++) {
            bf16x8 bfr = *(const bf16x8*)(pw2T + (w * 16 + ln) * 128 +
                                          ks * 32 + q * 8);
#pragma unroll
            for (int rt = 0; rt < 4; rt++) {
                bf16x8 afr = *(const bf16x8*)&acts[rt * 16 + ln][0 + ks * 32 + q * 8];
                pc[rt] = __builtin_amdgcn_mfma_f32_16x16x32_bf16(afr, bfr, pc[rt], 0, 0, 0);
            }
        }
        int col = w * 16 + ln;
        float bias = pb2[col];
#pragma unroll
        for (int rt = 0; rt < 4; rt++)
#pragma unroll
            for (int i = 0; i < 4; i++) {
                int row = rt * 16 + q * 4 + i;
                h2s[row][col] = f2b(fmaxf(pc[rt][i] + bias, 0.f));
            }
    }
    __syncthreads();

    // phase C3: probs; C4: directions (scalar heads, 64 rows each)
    if (t < 64) {
        float s = pb3[0];
#pragma unroll 8
        for (int k = 0; k < 64; k++) s += b2f(h2s[t][k]) * pw3[k];
        float pr = 1.f / (1.f + __expf(-s));
        out[r0 + t] = pr;
    } else if (t < 128) {
        int row = t - 64;
        float s = db2[0];
#pragma unroll 8
        for (int k = 0; k < 64; k++) s += b2f(acts[row][128 + k]) * dw2[k];
        float dir = (1.f / (1.f + __expf(-s))) * 1.57079632679489662f;
        out[(size_t)N + r0 + row] = dir;
    }
}

extern "C" void kernel_launch(void* const* d_in, const int* in_sizes, int n_in,
                              void* d_out, int out_size, void* d_ws, size_t ws_size,
                              hipStream_t stream) {
    const float* beliefs = (const float*)d_in[0];
    const int* src = (const int*)d_in[1];
    const int* tgt = (const int*)d_in[2];
    const float* pw1 = (const float*)d_in[3];
    const float* pb1 = (const float*)d_in[4];
    const float* pw2 = (const float*)d_in[5];
    const float* pb2 = (const float*)d_in[6];
    const float* pw3 = (const float*)d_in[7];
    const float* pb3 = (const float*)d_in[8];
    const float* dw1 = (const float*)d_in[9];
    const float* db1 = (const float*)d_in[10];
    const float* dw2 = (const float*)d_in[11];
    const float* db2 = (const float*)d_in[12];
    const float* rw1 = (const float*)d_in[13];
    const float* rb1 = (const float*)d_in[14];
    const float* rw2 = (const float*)d_in[15];
    const float* rb2 = (const float*)d_in[16];

    short* ws = (short*)d_ws;
    short* WT   = ws;
    short* pw2T = ws + P2T_OFF;
    short* rw2T = ws + R2T_OFF;
    const int N = in_sizes[1];

    prep_kernel<<<(PREP_TOT + 255) / 256, 256, 0, stream>>>(pw1, dw1, rw1, pw2, rw2, ws);
    edge_main<<<N / 64, 256, 0, stream>>>(beliefs, src, tgt,
                                          pb1, db1, rb1,
                                          pb2, pw3, pb3,
                                          dw2, db2, rb2,
                                          WT, pw2T, rw2T,
                                          (float*)d_out, N);
}